// Round 3
// baseline (1206.655 us; speedup 1.0000x reference)
//
#include <hip/hip_runtime.h>
#include <math.h>

// InteractionPPBlock — round 5: VALU-diet for the MFMA trunk kernels.
//   - silu via v_rcp_f32 (1 op) instead of exact f32 division (~9 ops);
//     bf16 outputs make the 1-ulp rcp error invisible.
//   - bias folded into MFMA accumulator init (C-in = bias broadcast):
//     deletes per-element bias add + select in every epilogue.
//   - post_kernel occupancy 3 -> 4 blocks/CU.
// Triplet phase (CSR build + gather) unchanged from round 4.

#define E_N 262144
#define T_N 2097152
#define LDX 136   // 128 + 8 bf16 pad -> 272B row stride (16B-aligned, banks spread)

typedef __bf16 bf16_t;
typedef _Float16 f16_t;
typedef __attribute__((ext_vector_type(8))) __bf16 bf16x8;
typedef __attribute__((ext_vector_type(2))) __bf16 bf16x2;
typedef __attribute__((ext_vector_type(4))) float f32x4;

#define MFMA_B16(a, b, c) __builtin_amdgcn_mfma_f32_16x16x32_bf16(a, b, c, 0, 0, 0)

__device__ __forceinline__ float silu_f(float x) {
    // x * rcp(1+exp(-x)); rcp error ~1 ulp, output is bf16 -> invisible.
    return x * __builtin_amdgcn_rcpf(1.0f + __expf(-x));
}

// ---------------- weight swizzle prep ----------------
// dst layout: frag f = ct*KK + kk; element ((f*64 + lane)*8 + j) = B[kk*32+q*8+j][ct*16+c]
struct SwDesc { const float* src; bf16_t* dst; int Ksrc, KK, N, tbase; };
struct SwArgs { SwDesc d[12]; };

__global__ __launch_bounds__(256) void swizzle_kernel(SwArgs a, int total) {
    int t = blockIdx.x * 256 + threadIdx.x;
    if (t >= total) return;
    int i = 0;
#pragma unroll
    for (int j = 1; j < 12; j++) if (t >= a.d[j].tbase) i = j;
    SwDesc d = a.d[i];
    int lt = t - d.tbase;
    int lane = lt & 63, f = lt >> 6;
    int kk = f % d.KK, ct = f / d.KK;
    int q = lane >> 4, c = lane & 15, col = ct * 16 + c;
    bf16x8 v;
#pragma unroll
    for (int j = 0; j < 8; j++) {
        int k = kk * 32 + q * 8 + j;
        v[j] = (k < d.Ksrc) ? (bf16_t)d.src[(size_t)k * d.N + col] : (bf16_t)0.0f;
    }
    *(bf16x8*)(d.dst + (size_t)lt * 8) = v;
}

__global__ __launch_bounds__(256) void zero_kernel(float4* __restrict__ p, int n4) {
    int i = blockIdx.x * 256 + threadIdx.x;
    if (i < n4) p[i] = make_float4(0.f, 0.f, 0.f, 0.f);
}

// ---------------- MFMA stage: acc[rt][ctl] = X(64 x 32*KK) @ W + bias(col)
// bias enters as the accumulator init (D-layout cols are lane-constant).
template<int KK>
__device__ __forceinline__ void mfma_stage(const bf16_t* __restrict__ X,      // LDS, stride LDX
                                           const bf16_t* __restrict__ Wsw,    // global, swizzled
                                           int lane, int ct0, f32x4 acc[4][2],
                                           float i0, float i1) {
    const int q = lane >> 4, l15 = lane & 15;
    bf16x8 Bf[2][KK];
#pragma unroll
    for (int c = 0; c < 2; c++)
#pragma unroll
        for (int kk = 0; kk < KK; kk++)
            Bf[c][kk] = *(const bf16x8*)(Wsw + ((size_t)((ct0 + c) * KK + kk) * 64 + lane) * 8);
    f32x4 z0 = {i0, i0, i0, i0};
    f32x4 z1 = {i1, i1, i1, i1};
#pragma unroll
    for (int rt = 0; rt < 4; rt++) { acc[rt][0] = z0; acc[rt][1] = z1; }
#pragma unroll
    for (int kk = 0; kk < KK; kk++) {
#pragma unroll
        for (int rt = 0; rt < 4; rt++) {
            bf16x8 a = *(const bf16x8*)(X + (rt * 16 + l15) * LDX + kk * 32 + q * 8);
            acc[rt][0] = MFMA_B16(a, Bf[0][kk], acc[rt][0]);
            acc[rt][1] = MFMA_B16(a, Bf[1][kk], acc[rt][1]);
        }
    }
}

// ---------------- edge kernel ----------------
__global__ __launch_bounds__(256, 3) void edge_kernel(
    const float* __restrict__ m, const float* __restrict__ rbf,
    const float* __restrict__ W_rbf1, const bf16_t* __restrict__ W_rbf2sw,
    const bf16_t* __restrict__ W_jisw, const float* __restrict__ b_ji,
    const bf16_t* __restrict__ W_kjsw, const float* __restrict__ b_kj,
    const bf16_t* __restrict__ W_downsw,
    bf16_t* __restrict__ x_ji_bf, f16_t* __restrict__ x_kj) {
    __shared__ bf16_t Xm[64 * LDX];
    __shared__ bf16_t Xt[64 * LDX];
    __shared__ bf16_t hb[64 * 32];   // h zero-padded K 8->32
    __shared__ float rl[64 * 6];
    const int tid = threadIdx.x;
    const int lane = tid & 63, wave = tid >> 6;
    const int q = lane >> 4, l15 = lane & 15;
    const int ct0 = wave * 2, wc0 = wave * 32;
    const int r0 = blockIdx.x * 64;

    // stage m tile -> bf16 LDS
#pragma unroll
    for (int i = 0; i < 8; i++) {
        int e = (i * 256 + tid) * 4;
        int row = e >> 7, col = e & 127;
        float4 v = *(const float4*)(m + (size_t)(r0 + row) * 128 + col);
        bf16_t* d = Xm + row * LDX + col;
        d[0] = (bf16_t)v.x; d[1] = (bf16_t)v.y; d[2] = (bf16_t)v.z; d[3] = (bf16_t)v.w;
    }
    for (int i = tid; i < 64 * 6; i += 256) rl[i] = rbf[(size_t)r0 * 6 + i];
    for (int i = tid; i < 64 * 32; i += 256) hb[i] = (bf16_t)0.0f;
    __syncthreads();

    {   // h = rbf @ W_rbf1 [64][8] -> hb (bf16, zero-padded to K=32)
        int tt = tid >> 2, b0 = (tid & 3) << 1;
        float s0 = 0.f, s1 = 0.f;
#pragma unroll
        for (int k = 0; k < 6; k++) {
            float v = rl[tt * 6 + k];
            s0 = fmaf(v, W_rbf1[k * 8 + b0], s0);
            s1 = fmaf(v, W_rbf1[k * 8 + b0 + 1], s1);
        }
        hb[tt * 32 + b0] = (bf16_t)s0;
        hb[tt * 32 + b0 + 1] = (bf16_t)s1;
    }
    __syncthreads();

    // rbf_e = hb @ W_rbf2  (KK=1, zero-padded)
    f32x4 rbfe[4][2];
    {
        bf16x8 B0 = *(const bf16x8*)(W_rbf2sw + ((size_t)(ct0 + 0) * 64 + lane) * 8);
        bf16x8 B1 = *(const bf16x8*)(W_rbf2sw + ((size_t)(ct0 + 1) * 64 + lane) * 8);
        f32x4 z = {0.f, 0.f, 0.f, 0.f};
#pragma unroll
        for (int rt = 0; rt < 4; rt++) {
            bf16x8 a = *(const bf16x8*)(hb + (rt * 16 + l15) * 32 + q * 8);
            rbfe[rt][0] = MFMA_B16(a, B0, z);
            rbfe[rt][1] = MFMA_B16(a, B1, z);
        }
    }

    f32x4 acc[4][2];

    // x_ji = silu(m @ W_ji + b_ji) -> global bf16
    mfma_stage<4>(Xm, W_jisw, lane, ct0, acc, b_ji[wc0 + l15], b_ji[wc0 + 16 + l15]);
#pragma unroll
    for (int rt = 0; rt < 4; rt++)
#pragma unroll
        for (int c = 0; c < 2; c++)
#pragma unroll
            for (int r = 0; r < 4; r++) {
                int row = rt * 16 + q * 4 + r, col = wc0 + c * 16 + l15;
                x_ji_bf[(size_t)(r0 + row) * 128 + col] = (bf16_t)silu_f(acc[rt][c][r]);
            }

    // t = silu(m @ W_kj + b_kj) * rbf_e -> Xt (bf16)
    mfma_stage<4>(Xm, W_kjsw, lane, ct0, acc, b_kj[wc0 + l15], b_kj[wc0 + 16 + l15]);
#pragma unroll
    for (int rt = 0; rt < 4; rt++)
#pragma unroll
        for (int c = 0; c < 2; c++)
#pragma unroll
            for (int r = 0; r < 4; r++) {
                int row = rt * 16 + q * 4 + r, col = wc0 + c * 16 + l15;
                Xt[row * LDX + col] = (bf16_t)(silu_f(acc[rt][c][r]) * rbfe[rt][c][r]);
            }
    __syncthreads();

    // x_kj = silu(Xt @ W_down) [64 cols] -> fp16 global; wave handles ct = wave
    {
        bf16x8 Bf[4];
#pragma unroll
        for (int kk = 0; kk < 4; kk++)
            Bf[kk] = *(const bf16x8*)(W_downsw + ((size_t)(wave * 4 + kk) * 64 + lane) * 8);
        f32x4 a2[4];
        f32x4 z = {0.f, 0.f, 0.f, 0.f};
#pragma unroll
        for (int rt = 0; rt < 4; rt++) a2[rt] = z;
#pragma unroll
        for (int kk = 0; kk < 4; kk++)
#pragma unroll
            for (int rt = 0; rt < 4; rt++) {
                bf16x8 a = *(const bf16x8*)(Xt + (rt * 16 + l15) * LDX + kk * 32 + q * 8);
                a2[rt] = MFMA_B16(a, Bf[kk], a2[rt]);
            }
#pragma unroll
        for (int rt = 0; rt < 4; rt++)
#pragma unroll
            for (int r = 0; r < 4; r++) {
                int row = rt * 16 + q * 4 + r, col = wave * 16 + l15;
                x_kj[(size_t)(r0 + row) * 64 + col] = (f16_t)silu_f(a2[rt][r]);
            }
    }
}

// ---------------- triplet phase: CSR build + gather ----------------

// hist: dst histogram only
__global__ __launch_bounds__(256) void hist_kernel(
    const int* __restrict__ dst_idx, int* __restrict__ counts) {
    int t = blockIdx.x * 256 + threadIdx.x;
    atomicAdd(&counts[dst_idx[t]], 1);
}

// scan1: per-block (1024 counts) exclusive scan + block total
__global__ __launch_bounds__(256) void scan1_kernel(
    const int4* __restrict__ c4, int* __restrict__ offs, int* __restrict__ bsums) {
    __shared__ int sc[256];
    const int tid = threadIdx.x;
    int idx = blockIdx.x * 256 + tid;
    int4 c = c4[idx];
    int s = c.x + c.y + c.z + c.w;
    sc[tid] = s;
    __syncthreads();
#pragma unroll
    for (int d = 1; d < 256; d <<= 1) {
        int t = (tid >= d) ? sc[tid - d] : 0;
        __syncthreads();
        sc[tid] += t;
        __syncthreads();
    }
    int excl = sc[tid] - s;
    int4 o;
    o.x = excl; o.y = excl + c.x; o.z = o.y + c.y; o.w = o.z + c.z;
    ((int4*)offs)[idx] = o;
    if (tid == 255) bsums[blockIdx.x] = sc[255];
}

// scan2: exclusive scan of the 256 block sums
__global__ __launch_bounds__(256) void scan2_kernel(
    const int* __restrict__ bsums, int* __restrict__ bsums2) {
    __shared__ int sc[256];
    const int tid = threadIdx.x;
    int v = bsums[tid];
    sc[tid] = v;
    __syncthreads();
#pragma unroll
    for (int d = 1; d < 256; d <<= 1) {
        int t = (tid >= d) ? sc[tid - d] : 0;
        __syncthreads();
        sc[tid] += t;
        __syncthreads();
    }
    bsums2[tid] = sc[tid] - v;
}

// scan3: add block base; also init cursor = offsets
__global__ __launch_bounds__(256) void scan3_kernel(
    int* __restrict__ offs, const int* __restrict__ bsums2, int* __restrict__ cursor) {
    int i = blockIdx.x * 256 + threadIdx.x;
    int o = offs[i] + bsums2[i >> 10];
    offs[i] = o;
    cursor[i] = o;
}

// fillB: stream sbf, compute B = sbf@W_sbf1, scatter into CSR order.
// 64 triplets/block; 4 threads cooperate per triplet (2 of 8 B-cols each).
__global__ __launch_bounds__(256) void fillB_kernel(
    const float* __restrict__ sbf, const int* __restrict__ src_idx,
    const int* __restrict__ dst_idx, const float* __restrict__ W_sbf1,
    int* __restrict__ cursor,
    int* __restrict__ srcrec, bf16_t* __restrict__ Bs) {
    __shared__ float S[64 * 42];
    __shared__ float W1l[336];
    __shared__ int posS[64];
    const int tid = threadIdx.x;
    const int t0 = blockIdx.x * 64;
    {
        const float4* s4 = (const float4*)(sbf + (size_t)t0 * 42);
        float4* d4 = (float4*)S;
        for (int i = tid; i < 672; i += 256) d4[i] = s4[i];
    }
    for (int i = tid; i < 336; i += 256) W1l[i] = W_sbf1[i];
    if (tid < 64) {
        int t = t0 + tid;
        int d = dst_idx[t];
        int pos = atomicAdd(&cursor[d], 1);
        posS[tid] = pos;
        srcrec[pos] = src_idx[t];
    }
    __syncthreads();

    int tt = tid >> 2, b0 = (tid & 3) << 1;
    float s0 = 0.f, s1 = 0.f;
#pragma unroll
    for (int k = 0; k < 42; k++) {
        float v = S[tt * 42 + k];
        s0 = fmaf(v, W1l[k * 8 + b0], s0);
        s1 = fmaf(v, W1l[k * 8 + b0 + 1], s1);
    }
    int pos = posS[tt];
    bf16x2 pr;
    pr[0] = (bf16_t)s0;
    pr[1] = (bf16_t)s1;
    *(bf16x2*)(Bs + (size_t)pos * 8 + b0) = pr;
}

// gather: one wave per destination edge; lanes = 64 channels; unroll-8
// batched independent loads; f32 register sum; single bf16 store.
__global__ __launch_bounds__(256) void gather_kernel(
    const int* __restrict__ offs, const int* __restrict__ counts,
    const int* __restrict__ srcrec, const bf16_t* __restrict__ Bs,
    const float* __restrict__ W_sbf2, const f16_t* __restrict__ xk,
    bf16_t* __restrict__ m_upd) {
    __shared__ float w2s[512];
    const int tid = threadIdx.x;
    w2s[tid] = W_sbf2[tid];
    w2s[tid + 256] = W_sbf2[tid + 256];
    __syncthreads();
    const int wave = tid >> 6, lane = tid & 63;
    const int e = blockIdx.x * 4 + wave;
    const int start = __builtin_amdgcn_readfirstlane(offs[e]);
    const int cnt   = __builtin_amdgcn_readfirstlane(counts[e]);
    float w2r[8];
#pragma unroll
    for (int k = 0; k < 8; k++) w2r[k] = w2s[k * 64 + lane];
    float acc = 0.f;
    for (int i0 = 0; i0 < cnt; i0 += 8) {
        const int rem = cnt - i0;
        int idxs[8];
#pragma unroll
        for (int j = 0; j < 8; j++) idxs[j] = start + i0 + ((j < rem) ? j : 0);
        int se[8];
#pragma unroll
        for (int j = 0; j < 8; j++) se[j] = srcrec[idxs[j]];
        bf16x8 bv[8];
#pragma unroll
        for (int j = 0; j < 8; j++) bv[j] = *(const bf16x8*)(Bs + (size_t)idxs[j] * 8);
        float xv[8];
#pragma unroll
        for (int j = 0; j < 8; j++) xv[j] = (float)xk[(size_t)se[j] * 64 + lane];
#pragma unroll
        for (int j = 0; j < 8; j++) {
            float s = 0.f;
#pragma unroll
            for (int k = 0; k < 8; k++) s = fmaf((float)bv[j][k], w2r[k], s);
            if (j < rem) acc = fmaf(xv[j], s, acc);
        }
    }
    m_upd[(size_t)e * 64 + lane] = (bf16_t)acc;
}

// ---------------- post chain ----------------
__global__ __launch_bounds__(256, 4) void post_kernel(
    const float* __restrict__ m, const bf16_t* __restrict__ x_ji_bf,
    const bf16_t* __restrict__ m_up,
    const bf16_t* __restrict__ W_upsw,
    const bf16_t* __restrict__ Wb1sw, const float* __restrict__ bb1,
    const bf16_t* __restrict__ Wb2sw, const float* __restrict__ bb2,
    const bf16_t* __restrict__ Wfinsw, const float* __restrict__ b_final,
    const bf16_t* __restrict__ Wa1s0, const bf16_t* __restrict__ Wa1s1,
    const float* __restrict__ ba1,
    const bf16_t* __restrict__ Wa2s0, const bf16_t* __restrict__ Wa2s1,
    const float* __restrict__ ba2,
    float* __restrict__ out) {
    __shared__ bf16_t X0[64 * LDX];
    __shared__ bf16_t X1[64 * LDX];
    const int tid = threadIdx.x;
    const int lane = tid & 63, wave = tid >> 6;
    const int q = lane >> 4, l15 = lane & 15;
    const int ct0 = wave * 2, wc0 = wave * 32;
    const int r0 = blockIdx.x * 64;

    // stage m_up [64][64] bf16 -> X0
#pragma unroll
    for (int i = 0; i < 2; i++) {
        int idx = i * 256 + tid;
        int row = idx >> 3, col = (idx & 7) * 8;
        *(bf16x8*)(X0 + row * LDX + col) =
            *(const bf16x8*)(m_up + (size_t)(r0 + row) * 64 + col);
    }
    __syncthreads();

    f32x4 acc[4][2];
    float res[4][2][4];

    // s0: U = silu(X0 @ W_up) + x_ji ; res=U ; X1=bf16(U)
    mfma_stage<2>(X0, W_upsw, lane, ct0, acc, 0.f, 0.f);
#pragma unroll
    for (int rt = 0; rt < 4; rt++)
#pragma unroll
        for (int c = 0; c < 2; c++)
#pragma unroll
            for (int r = 0; r < 4; r++) {
                int row = rt * 16 + q * 4 + r, col = wc0 + c * 16 + l15;
                float v = silu_f(acc[rt][c][r]) + (float)x_ji_bf[(size_t)(r0 + row) * 128 + col];
                res[rt][c][r] = v;
                X1[row * LDX + col] = (bf16_t)v;
            }
    __syncthreads();

    // s1: H1 = silu(X1 @ Wb1 + bb1) -> X0
    mfma_stage<4>(X1, Wb1sw, lane, ct0, acc, bb1[wc0 + l15], bb1[wc0 + 16 + l15]);
#pragma unroll
    for (int rt = 0; rt < 4; rt++)
#pragma unroll
        for (int c = 0; c < 2; c++)
#pragma unroll
            for (int r = 0; r < 4; r++) {
                int row = rt * 16 + q * 4 + r, col = wc0 + c * 16 + l15;
                X0[row * LDX + col] = (bf16_t)silu_f(acc[rt][c][r]);
            }
    __syncthreads();

    // s2: res += silu(X0 @ Wb2 + bb2) ; X1 = bf16(res)
    mfma_stage<4>(X0, Wb2sw, lane, ct0, acc, bb2[wc0 + l15], bb2[wc0 + 16 + l15]);
#pragma unroll
    for (int rt = 0; rt < 4; rt++)
#pragma unroll
        for (int c = 0; c < 2; c++)
#pragma unroll
            for (int r = 0; r < 4; r++) {
                int row = rt * 16 + q * 4 + r, col = wc0 + c * 16 + l15;
                float v = res[rt][c][r] + silu_f(acc[rt][c][r]);
                res[rt][c][r] = v;
                X1[row * LDX + col] = (bf16_t)v;
            }
    __syncthreads();

    // s3: res = silu(X1 @ W_final + b_final) + m ; X0 = bf16(res)
    mfma_stage<4>(X1, Wfinsw, lane, ct0, acc, b_final[wc0 + l15], b_final[wc0 + 16 + l15]);
#pragma unroll
    for (int rt = 0; rt < 4; rt++)
#pragma unroll
        for (int c = 0; c < 2; c++)
#pragma unroll
            for (int r = 0; r < 4; r++) {
                int row = rt * 16 + q * 4 + r, col = wc0 + c * 16 + l15;
                float v = silu_f(acc[rt][c][r]) + m[(size_t)(r0 + row) * 128 + col];
                res[rt][c][r] = v;
                X0[row * LDX + col] = (bf16_t)v;
            }
    __syncthreads();

    // s4: H = silu(X0 @ Wa1[0] + ba1[0]) -> X1
    mfma_stage<4>(X0, Wa1s0, lane, ct0, acc, ba1[wc0 + l15], ba1[wc0 + 16 + l15]);
#pragma unroll
    for (int rt = 0; rt < 4; rt++)
#pragma unroll
        for (int c = 0; c < 2; c++)
#pragma unroll
            for (int r = 0; r < 4; r++) {
                int row = rt * 16 + q * 4 + r, col = wc0 + c * 16 + l15;
                X1[row * LDX + col] = (bf16_t)silu_f(acc[rt][c][r]);
            }
    __syncthreads();

    // s5: res += silu(X1 @ Wa2[0] + ba2[0]) ; X0 = bf16(res)
    mfma_stage<4>(X1, Wa2s0, lane, ct0, acc, ba2[wc0 + l15], ba2[wc0 + 16 + l15]);
#pragma unroll
    for (int rt = 0; rt < 4; rt++)
#pragma unroll
        for (int c = 0; c < 2; c++)
#pragma unroll
            for (int r = 0; r < 4; r++) {
                int row = rt * 16 + q * 4 + r, col = wc0 + c * 16 + l15;
                float v = res[rt][c][r] + silu_f(acc[rt][c][r]);
                res[rt][c][r] = v;
                X0[row * LDX + col] = (bf16_t)v;
            }
    __syncthreads();

    // s6: H = silu(X0 @ Wa1[1] + ba1[1]) -> X1
    mfma_stage<4>(X0, Wa1s1, lane, ct0, acc, ba1[128 + wc0 + l15], ba1[128 + wc0 + 16 + l15]);
#pragma unroll
    for (int rt = 0; rt < 4; rt++)
#pragma unroll
        for (int c = 0; c < 2; c++)
#pragma unroll
            for (int r = 0; r < 4; r++) {
                int row = rt * 16 + q * 4 + r, col = wc0 + c * 16 + l15;
                X1[row * LDX + col] = (bf16_t)silu_f(acc[rt][c][r]);
            }
    __syncthreads();

    // s7: out = res + silu(X1 @ Wa2[1] + ba2[1])
    mfma_stage<4>(X1, Wa2s1, lane, ct0, acc, ba2[128 + wc0 + l15], ba2[128 + wc0 + 16 + l15]);
#pragma unroll
    for (int rt = 0; rt < 4; rt++)
#pragma unroll
        for (int c = 0; c < 2; c++)
#pragma unroll
            for (int r = 0; r < 4; r++) {
                int row = rt * 16 + q * 4 + r, col = wc0 + c * 16 + l15;
                out[(size_t)(r0 + row) * 128 + col] = res[rt][c][r] + silu_f(acc[rt][c][r]);
            }
}

extern "C" void kernel_launch(void* const* d_in, const int* in_sizes, int n_in,
                              void* d_out, int out_size, void* d_ws, size_t ws_size,
                              hipStream_t stream) {
    const float* m      = (const float*)d_in[0];
    const float* rbf    = (const float*)d_in[1];
    const float* sbf    = (const float*)d_in[2];
    const int*   src    = (const int*)d_in[3];
    const int*   dst    = (const int*)d_in[4];
    const float* W_rbf1 = (const float*)d_in[5];
    const float* W_rbf2 = (const float*)d_in[6];
    const float* W_sbf1 = (const float*)d_in[7];
    const float* W_sbf2 = (const float*)d_in[8];
    const float* W_ji   = (const float*)d_in[9];
    const float* b_ji   = (const float*)d_in[10];
    const float* W_kj   = (const float*)d_in[11];
    const float* b_kj   = (const float*)d_in[12];
    const float* W_down = (const float*)d_in[13];
    const float* W_up   = (const float*)d_in[14];
    const float* Wb1    = (const float*)d_in[15];
    const float* bb1    = (const float*)d_in[16];
    const float* Wb2    = (const float*)d_in[17];
    const float* bb2    = (const float*)d_in[18];
    const float* W_final= (const float*)d_in[19];
    const float* b_final= (const float*)d_in[20];
    const float* Wa1    = (const float*)d_in[21];
    const float* ba1    = (const float*)d_in[22];
    const float* Wa2    = (const float*)d_in[23];
    const float* ba2    = (const float*)d_in[24];
    float* out = (float*)d_out;

    // ws layout:
    //   x_ji bf16 [E,128] | x_kj f16 [E,64] | m_upd bf16 [E,64]
    //   | Bs bf16 [T,8] (CSR order) | srcrec int [T]
    //   | counts int [E] | offs int [E] | cursor int [E]
    //   | bsums int[256]+bsums2 int[256] | swizzled weights
    size_t off_xkj  = (size_t)E_N * 128 * sizeof(bf16_t);
    size_t off_mup  = off_xkj  + (size_t)E_N * 64 * sizeof(f16_t);
    size_t off_Bs   = off_mup  + (size_t)E_N * 64 * sizeof(bf16_t);
    size_t off_src  = off_Bs   + (size_t)T_N * 8 * sizeof(bf16_t);
    size_t off_cnt  = off_src  + (size_t)T_N * sizeof(int);
    size_t off_offs = off_cnt  + (size_t)E_N * sizeof(int);
    size_t off_cur  = off_offs + (size_t)E_N * sizeof(int);
    size_t off_bs   = off_cur  + (size_t)E_N * sizeof(int);
    size_t off_w    = off_bs   + 4096;
    size_t w_elems = 167936;
    if (ws_size < off_w + w_elems * sizeof(bf16_t)) return;

    bf16_t* x_ji_bf = (bf16_t*)d_ws;
    f16_t*  x_kj    = (f16_t*)((char*)d_ws + off_xkj);
    bf16_t* m_upd   = (bf16_t*)((char*)d_ws + off_mup);
    bf16_t* Bs      = (bf16_t*)((char*)d_ws + off_Bs);
    int*    srcrec  = (int*)((char*)d_ws + off_src);
    int*    counts  = (int*)((char*)d_ws + off_cnt);
    int*    offs    = (int*)((char*)d_ws + off_offs);
    int*    cursor  = (int*)((char*)d_ws + off_cur);
    int*    bsums   = (int*)((char*)d_ws + off_bs);
    int*    bsums2  = bsums + 256;
    bf16_t* wts     = (bf16_t*)((char*)d_ws + off_w);

    bf16_t* W_rbf2sw = wts;            // 8 frags   (K 8->32 pad, N=128)
    bf16_t* W_jisw   = wts + 4096;     // 32 frags
    bf16_t* W_kjsw   = wts + 20480;    // 32
    bf16_t* W_downsw = wts + 36864;    // 16 (K=128, N=64)
    bf16_t* W_upsw   = wts + 45056;    // 16 (K=64, N=128)
    bf16_t* Wb1sw    = wts + 53248;
    bf16_t* Wb2sw    = wts + 69632;
    bf16_t* Wfinsw   = wts + 86016;
    bf16_t* Wa1sw0   = wts + 102400;
    bf16_t* Wa1sw1   = wts + 118784;
    bf16_t* Wa2sw0   = wts + 135168;
    bf16_t* Wa2sw1   = wts + 151552;

    SwArgs sa;
    int tb = 0;
    auto set = [&](int i, const float* s, bf16_t* d, int Ksrc, int KK, int N) {
        sa.d[i] = SwDesc{s, d, Ksrc, KK, N, tb};
        tb += (N / 16) * KK * 64;
    };
    set(0,  W_rbf2,        W_rbf2sw, 8,   1, 128);
    set(1,  W_ji,          W_jisw,   128, 4, 128);
    set(2,  W_kj,          W_kjsw,   128, 4, 128);
    set(3,  W_down,        W_downsw, 128, 4, 64);
    set(4,  W_up,          W_upsw,   64,  2, 128);
    set(5,  Wb1,           Wb1sw,    128, 4, 128);
    set(6,  Wb2,           Wb2sw,    128, 4, 128);
    set(7,  W_final,       Wfinsw,   128, 4, 128);
    set(8,  Wa1,           Wa1sw0,   128, 4, 128);
    set(9,  Wa1 + 16384,   Wa1sw1,   128, 4, 128);
    set(10, Wa2,           Wa2sw0,   128, 4, 128);
    set(11, Wa2 + 16384,   Wa2sw1,   128, 4, 128);
    int total = tb;  // 20992

    swizzle_kernel<<<(total + 255) / 256, 256, 0, stream>>>(sa, total);

    // zero counts (E ints = 65536 float4)
    zero_kernel<<<256, 256, 0, stream>>>((float4*)counts, E_N / 4);

    // CSR build (fused B-factor scatter)
    hist_kernel<<<T_N / 256, 256, 0, stream>>>(dst, counts);
    scan1_kernel<<<E_N / 1024, 256, 0, stream>>>((const int4*)counts, offs, bsums);
    scan2_kernel<<<1, 256, 0, stream>>>(bsums, bsums2);
    scan3_kernel<<<E_N / 256, 256, 0, stream>>>(offs, bsums2, cursor);
    fillB_kernel<<<T_N / 64, 256, 0, stream>>>(sbf, src, dst, W_sbf1,
                                               cursor, srcrec, Bs);

    edge_kernel<<<E_N / 64, 256, 0, stream>>>(m, rbf, W_rbf1, W_rbf2sw,
                                              W_jisw, b_ji, W_kjsw, b_kj, W_downsw,
                                              x_ji_bf, x_kj);

    gather_kernel<<<E_N / 4, 256, 0, stream>>>(offs, counts, srcrec,
                                               Bs, W_sbf2, x_kj, m_upd);

    post_kernel<<<E_N / 64, 256, 0, stream>>>(m, x_ji_bf, m_upd, W_upsw,
                                              Wb1sw, bb1, Wb2sw, bb2,
                                              Wfinsw, b_final,
                                              Wa1sw0, Wa1sw1, ba1,
                                              Wa2sw0, Wa2sw1, ba2, out);
}

// Round 4
// 1117.146 us; speedup vs baseline: 1.0801x; 1.0801x over previous
//
#include <hip/hip_runtime.h>
#include <math.h>

// InteractionPPBlock — round 6: fix round-5's scratch-spill regression.
//   - post_kernel back to __launch_bounds__(256,3): 170 VGPR/wave budget,
//     res/acc/fragments stay in registers (round 5's (256,4) squeezed to
//     64 VGPR and spilled -> +350 MB HBM traffic, +30 us).
//   - KEEP the VALU diet: silu via v_rcp_f32, bias folded into MFMA C-in.
// Triplet phase (CSR build + gather) unchanged.

#define E_N 262144
#define T_N 2097152
#define LDX 136   // 128 + 8 bf16 pad -> 272B row stride (16B-aligned, banks spread)

typedef __bf16 bf16_t;
typedef _Float16 f16_t;
typedef __attribute__((ext_vector_type(8))) __bf16 bf16x8;
typedef __attribute__((ext_vector_type(2))) __bf16 bf16x2;
typedef __attribute__((ext_vector_type(4))) float f32x4;

#define MFMA_B16(a, b, c) __builtin_amdgcn_mfma_f32_16x16x32_bf16(a, b, c, 0, 0, 0)

__device__ __forceinline__ float silu_f(float x) {
    // x * rcp(1+exp(-x)); rcp error ~1 ulp, output is bf16 -> invisible.
    return x * __builtin_amdgcn_rcpf(1.0f + __expf(-x));
}

// ---------------- weight swizzle prep ----------------
// dst layout: frag f = ct*KK + kk; element ((f*64 + lane)*8 + j) = B[kk*32+q*8+j][ct*16+c]
struct SwDesc { const float* src; bf16_t* dst; int Ksrc, KK, N, tbase; };
struct SwArgs { SwDesc d[12]; };

__global__ __launch_bounds__(256) void swizzle_kernel(SwArgs a, int total) {
    int t = blockIdx.x * 256 + threadIdx.x;
    if (t >= total) return;
    int i = 0;
#pragma unroll
    for (int j = 1; j < 12; j++) if (t >= a.d[j].tbase) i = j;
    SwDesc d = a.d[i];
    int lt = t - d.tbase;
    int lane = lt & 63, f = lt >> 6;
    int kk = f % d.KK, ct = f / d.KK;
    int q = lane >> 4, c = lane & 15, col = ct * 16 + c;
    bf16x8 v;
#pragma unroll
    for (int j = 0; j < 8; j++) {
        int k = kk * 32 + q * 8 + j;
        v[j] = (k < d.Ksrc) ? (bf16_t)d.src[(size_t)k * d.N + col] : (bf16_t)0.0f;
    }
    *(bf16x8*)(d.dst + (size_t)lt * 8) = v;
}

__global__ __launch_bounds__(256) void zero_kernel(float4* __restrict__ p, int n4) {
    int i = blockIdx.x * 256 + threadIdx.x;
    if (i < n4) p[i] = make_float4(0.f, 0.f, 0.f, 0.f);
}

// ---------------- MFMA stage: acc[rt][ctl] = X(64 x 32*KK) @ W + bias(col)
// bias enters as the accumulator init (D-layout cols are lane-constant).
template<int KK>
__device__ __forceinline__ void mfma_stage(const bf16_t* __restrict__ X,      // LDS, stride LDX
                                           const bf16_t* __restrict__ Wsw,    // global, swizzled
                                           int lane, int ct0, f32x4 acc[4][2],
                                           float i0, float i1) {
    const int q = lane >> 4, l15 = lane & 15;
    bf16x8 Bf[2][KK];
#pragma unroll
    for (int c = 0; c < 2; c++)
#pragma unroll
        for (int kk = 0; kk < KK; kk++)
            Bf[c][kk] = *(const bf16x8*)(Wsw + ((size_t)((ct0 + c) * KK + kk) * 64 + lane) * 8);
    f32x4 z0 = {i0, i0, i0, i0};
    f32x4 z1 = {i1, i1, i1, i1};
#pragma unroll
    for (int rt = 0; rt < 4; rt++) { acc[rt][0] = z0; acc[rt][1] = z1; }
#pragma unroll
    for (int kk = 0; kk < KK; kk++) {
#pragma unroll
        for (int rt = 0; rt < 4; rt++) {
            bf16x8 a = *(const bf16x8*)(X + (rt * 16 + l15) * LDX + kk * 32 + q * 8);
            acc[rt][0] = MFMA_B16(a, Bf[0][kk], acc[rt][0]);
            acc[rt][1] = MFMA_B16(a, Bf[1][kk], acc[rt][1]);
        }
    }
}

// ---------------- edge kernel ----------------
__global__ __launch_bounds__(256, 3) void edge_kernel(
    const float* __restrict__ m, const float* __restrict__ rbf,
    const float* __restrict__ W_rbf1, const bf16_t* __restrict__ W_rbf2sw,
    const bf16_t* __restrict__ W_jisw, const float* __restrict__ b_ji,
    const bf16_t* __restrict__ W_kjsw, const float* __restrict__ b_kj,
    const bf16_t* __restrict__ W_downsw,
    bf16_t* __restrict__ x_ji_bf, f16_t* __restrict__ x_kj) {
    __shared__ bf16_t Xm[64 * LDX];
    __shared__ bf16_t Xt[64 * LDX];
    __shared__ bf16_t hb[64 * 32];   // h zero-padded K 8->32
    __shared__ float rl[64 * 6];
    const int tid = threadIdx.x;
    const int lane = tid & 63, wave = tid >> 6;
    const int q = lane >> 4, l15 = lane & 15;
    const int ct0 = wave * 2, wc0 = wave * 32;
    const int r0 = blockIdx.x * 64;

    // stage m tile -> bf16 LDS
#pragma unroll
    for (int i = 0; i < 8; i++) {
        int e = (i * 256 + tid) * 4;
        int row = e >> 7, col = e & 127;
        float4 v = *(const float4*)(m + (size_t)(r0 + row) * 128 + col);
        bf16_t* d = Xm + row * LDX + col;
        d[0] = (bf16_t)v.x; d[1] = (bf16_t)v.y; d[2] = (bf16_t)v.z; d[3] = (bf16_t)v.w;
    }
    for (int i = tid; i < 64 * 6; i += 256) rl[i] = rbf[(size_t)r0 * 6 + i];
    for (int i = tid; i < 64 * 32; i += 256) hb[i] = (bf16_t)0.0f;
    __syncthreads();

    {   // h = rbf @ W_rbf1 [64][8] -> hb (bf16, zero-padded to K=32)
        int tt = tid >> 2, b0 = (tid & 3) << 1;
        float s0 = 0.f, s1 = 0.f;
#pragma unroll
        for (int k = 0; k < 6; k++) {
            float v = rl[tt * 6 + k];
            s0 = fmaf(v, W_rbf1[k * 8 + b0], s0);
            s1 = fmaf(v, W_rbf1[k * 8 + b0 + 1], s1);
        }
        hb[tt * 32 + b0] = (bf16_t)s0;
        hb[tt * 32 + b0 + 1] = (bf16_t)s1;
    }
    __syncthreads();

    // rbf_e = hb @ W_rbf2  (KK=1, zero-padded)
    f32x4 rbfe[4][2];
    {
        bf16x8 B0 = *(const bf16x8*)(W_rbf2sw + ((size_t)(ct0 + 0) * 64 + lane) * 8);
        bf16x8 B1 = *(const bf16x8*)(W_rbf2sw + ((size_t)(ct0 + 1) * 64 + lane) * 8);
        f32x4 z = {0.f, 0.f, 0.f, 0.f};
#pragma unroll
        for (int rt = 0; rt < 4; rt++) {
            bf16x8 a = *(const bf16x8*)(hb + (rt * 16 + l15) * 32 + q * 8);
            rbfe[rt][0] = MFMA_B16(a, B0, z);
            rbfe[rt][1] = MFMA_B16(a, B1, z);
        }
    }

    f32x4 acc[4][2];

    // x_ji = silu(m @ W_ji + b_ji) -> global bf16
    mfma_stage<4>(Xm, W_jisw, lane, ct0, acc, b_ji[wc0 + l15], b_ji[wc0 + 16 + l15]);
#pragma unroll
    for (int rt = 0; rt < 4; rt++)
#pragma unroll
        for (int c = 0; c < 2; c++)
#pragma unroll
            for (int r = 0; r < 4; r++) {
                int row = rt * 16 + q * 4 + r, col = wc0 + c * 16 + l15;
                x_ji_bf[(size_t)(r0 + row) * 128 + col] = (bf16_t)silu_f(acc[rt][c][r]);
            }

    // t = silu(m @ W_kj + b_kj) * rbf_e -> Xt (bf16)
    mfma_stage<4>(Xm, W_kjsw, lane, ct0, acc, b_kj[wc0 + l15], b_kj[wc0 + 16 + l15]);
#pragma unroll
    for (int rt = 0; rt < 4; rt++)
#pragma unroll
        for (int c = 0; c < 2; c++)
#pragma unroll
            for (int r = 0; r < 4; r++) {
                int row = rt * 16 + q * 4 + r, col = wc0 + c * 16 + l15;
                Xt[row * LDX + col] = (bf16_t)(silu_f(acc[rt][c][r]) * rbfe[rt][c][r]);
            }
    __syncthreads();

    // x_kj = silu(Xt @ W_down) [64 cols] -> fp16 global; wave handles ct = wave
    {
        bf16x8 Bf[4];
#pragma unroll
        for (int kk = 0; kk < 4; kk++)
            Bf[kk] = *(const bf16x8*)(W_downsw + ((size_t)(wave * 4 + kk) * 64 + lane) * 8);
        f32x4 a2[4];
        f32x4 z = {0.f, 0.f, 0.f, 0.f};
#pragma unroll
        for (int rt = 0; rt < 4; rt++) a2[rt] = z;
#pragma unroll
        for (int kk = 0; kk < 4; kk++)
#pragma unroll
            for (int rt = 0; rt < 4; rt++) {
                bf16x8 a = *(const bf16x8*)(Xt + (rt * 16 + l15) * LDX + kk * 32 + q * 8);
                a2[rt] = MFMA_B16(a, Bf[kk], a2[rt]);
            }
#pragma unroll
        for (int rt = 0; rt < 4; rt++)
#pragma unroll
            for (int r = 0; r < 4; r++) {
                int row = rt * 16 + q * 4 + r, col = wave * 16 + l15;
                x_kj[(size_t)(r0 + row) * 64 + col] = (f16_t)silu_f(a2[rt][r]);
            }
    }
}

// ---------------- triplet phase: CSR build + gather ----------------

// hist: dst histogram only
__global__ __launch_bounds__(256) void hist_kernel(
    const int* __restrict__ dst_idx, int* __restrict__ counts) {
    int t = blockIdx.x * 256 + threadIdx.x;
    atomicAdd(&counts[dst_idx[t]], 1);
}

// scan1: per-block (1024 counts) exclusive scan + block total
__global__ __launch_bounds__(256) void scan1_kernel(
    const int4* __restrict__ c4, int* __restrict__ offs, int* __restrict__ bsums) {
    __shared__ int sc[256];
    const int tid = threadIdx.x;
    int idx = blockIdx.x * 256 + tid;
    int4 c = c4[idx];
    int s = c.x + c.y + c.z + c.w;
    sc[tid] = s;
    __syncthreads();
#pragma unroll
    for (int d = 1; d < 256; d <<= 1) {
        int t = (tid >= d) ? sc[tid - d] : 0;
        __syncthreads();
        sc[tid] += t;
        __syncthreads();
    }
    int excl = sc[tid] - s;
    int4 o;
    o.x = excl; o.y = excl + c.x; o.z = o.y + c.y; o.w = o.z + c.z;
    ((int4*)offs)[idx] = o;
    if (tid == 255) bsums[blockIdx.x] = sc[255];
}

// scan2: exclusive scan of the 256 block sums
__global__ __launch_bounds__(256) void scan2_kernel(
    const int* __restrict__ bsums, int* __restrict__ bsums2) {
    __shared__ int sc[256];
    const int tid = threadIdx.x;
    int v = bsums[tid];
    sc[tid] = v;
    __syncthreads();
#pragma unroll
    for (int d = 1; d < 256; d <<= 1) {
        int t = (tid >= d) ? sc[tid - d] : 0;
        __syncthreads();
        sc[tid] += t;
        __syncthreads();
    }
    bsums2[tid] = sc[tid] - v;
}

// scan3: add block base; also init cursor = offsets
__global__ __launch_bounds__(256) void scan3_kernel(
    int* __restrict__ offs, const int* __restrict__ bsums2, int* __restrict__ cursor) {
    int i = blockIdx.x * 256 + threadIdx.x;
    int o = offs[i] + bsums2[i >> 10];
    offs[i] = o;
    cursor[i] = o;
}

// fillB: stream sbf, compute B = sbf@W_sbf1, scatter into CSR order.
// 64 triplets/block; 4 threads cooperate per triplet (2 of 8 B-cols each).
__global__ __launch_bounds__(256) void fillB_kernel(
    const float* __restrict__ sbf, const int* __restrict__ src_idx,
    const int* __restrict__ dst_idx, const float* __restrict__ W_sbf1,
    int* __restrict__ cursor,
    int* __restrict__ srcrec, bf16_t* __restrict__ Bs) {
    __shared__ float S[64 * 42];
    __shared__ float W1l[336];
    __shared__ int posS[64];
    const int tid = threadIdx.x;
    const int t0 = blockIdx.x * 64;
    {
        const float4* s4 = (const float4*)(sbf + (size_t)t0 * 42);
        float4* d4 = (float4*)S;
        for (int i = tid; i < 672; i += 256) d4[i] = s4[i];
    }
    for (int i = tid; i < 336; i += 256) W1l[i] = W_sbf1[i];
    if (tid < 64) {
        int t = t0 + tid;
        int d = dst_idx[t];
        int pos = atomicAdd(&cursor[d], 1);
        posS[tid] = pos;
        srcrec[pos] = src_idx[t];
    }
    __syncthreads();

    int tt = tid >> 2, b0 = (tid & 3) << 1;
    float s0 = 0.f, s1 = 0.f;
#pragma unroll
    for (int k = 0; k < 42; k++) {
        float v = S[tt * 42 + k];
        s0 = fmaf(v, W1l[k * 8 + b0], s0);
        s1 = fmaf(v, W1l[k * 8 + b0 + 1], s1);
    }
    int pos = posS[tt];
    bf16x2 pr;
    pr[0] = (bf16_t)s0;
    pr[1] = (bf16_t)s1;
    *(bf16x2*)(Bs + (size_t)pos * 8 + b0) = pr;
}

// gather: one wave per destination edge; lanes = 64 channels; unroll-8
// batched independent loads; f32 register sum; single bf16 store.
__global__ __launch_bounds__(256) void gather_kernel(
    const int* __restrict__ offs, const int* __restrict__ counts,
    const int* __restrict__ srcrec, const bf16_t* __restrict__ Bs,
    const float* __restrict__ W_sbf2, const f16_t* __restrict__ xk,
    bf16_t* __restrict__ m_upd) {
    __shared__ float w2s[512];
    const int tid = threadIdx.x;
    w2s[tid] = W_sbf2[tid];
    w2s[tid + 256] = W_sbf2[tid + 256];
    __syncthreads();
    const int wave = tid >> 6, lane = tid & 63;
    const int e = blockIdx.x * 4 + wave;
    const int start = __builtin_amdgcn_readfirstlane(offs[e]);
    const int cnt   = __builtin_amdgcn_readfirstlane(counts[e]);
    float w2r[8];
#pragma unroll
    for (int k = 0; k < 8; k++) w2r[k] = w2s[k * 64 + lane];
    float acc = 0.f;
    for (int i0 = 0; i0 < cnt; i0 += 8) {
        const int rem = cnt - i0;
        int idxs[8];
#pragma unroll
        for (int j = 0; j < 8; j++) idxs[j] = start + i0 + ((j < rem) ? j : 0);
        int se[8];
#pragma unroll
        for (int j = 0; j < 8; j++) se[j] = srcrec[idxs[j]];
        bf16x8 bv[8];
#pragma unroll
        for (int j = 0; j < 8; j++) bv[j] = *(const bf16x8*)(Bs + (size_t)idxs[j] * 8);
        float xv[8];
#pragma unroll
        for (int j = 0; j < 8; j++) xv[j] = (float)xk[(size_t)se[j] * 64 + lane];
#pragma unroll
        for (int j = 0; j < 8; j++) {
            float s = 0.f;
#pragma unroll
            for (int k = 0; k < 8; k++) s = fmaf((float)bv[j][k], w2r[k], s);
            if (j < rem) acc = fmaf(xv[j], s, acc);
        }
    }
    m_upd[(size_t)e * 64 + lane] = (bf16_t)acc;
}

// ---------------- post chain ----------------
__global__ __launch_bounds__(256, 3) void post_kernel(
    const float* __restrict__ m, const bf16_t* __restrict__ x_ji_bf,
    const bf16_t* __restrict__ m_up,
    const bf16_t* __restrict__ W_upsw,
    const bf16_t* __restrict__ Wb1sw, const float* __restrict__ bb1,
    const bf16_t* __restrict__ Wb2sw, const float* __restrict__ bb2,
    const bf16_t* __restrict__ Wfinsw, const float* __restrict__ b_final,
    const bf16_t* __restrict__ Wa1s0, const bf16_t* __restrict__ Wa1s1,
    const float* __restrict__ ba1,
    const bf16_t* __restrict__ Wa2s0, const bf16_t* __restrict__ Wa2s1,
    const float* __restrict__ ba2,
    float* __restrict__ out) {
    __shared__ bf16_t X0[64 * LDX];
    __shared__ bf16_t X1[64 * LDX];
    const int tid = threadIdx.x;
    const int lane = tid & 63, wave = tid >> 6;
    const int q = lane >> 4, l15 = lane & 15;
    const int ct0 = wave * 2, wc0 = wave * 32;
    const int r0 = blockIdx.x * 64;

    // stage m_up [64][64] bf16 -> X0
#pragma unroll
    for (int i = 0; i < 2; i++) {
        int idx = i * 256 + tid;
        int row = idx >> 3, col = (idx & 7) * 8;
        *(bf16x8*)(X0 + row * LDX + col) =
            *(const bf16x8*)(m_up + (size_t)(r0 + row) * 64 + col);
    }
    __syncthreads();

    f32x4 acc[4][2];
    float res[4][2][4];

    // s0: U = silu(X0 @ W_up) + x_ji ; res=U ; X1=bf16(U)
    mfma_stage<2>(X0, W_upsw, lane, ct0, acc, 0.f, 0.f);
#pragma unroll
    for (int rt = 0; rt < 4; rt++)
#pragma unroll
        for (int c = 0; c < 2; c++)
#pragma unroll
            for (int r = 0; r < 4; r++) {
                int row = rt * 16 + q * 4 + r, col = wc0 + c * 16 + l15;
                float v = silu_f(acc[rt][c][r]) + (float)x_ji_bf[(size_t)(r0 + row) * 128 + col];
                res[rt][c][r] = v;
                X1[row * LDX + col] = (bf16_t)v;
            }
    __syncthreads();

    // s1: H1 = silu(X1 @ Wb1 + bb1) -> X0
    mfma_stage<4>(X1, Wb1sw, lane, ct0, acc, bb1[wc0 + l15], bb1[wc0 + 16 + l15]);
#pragma unroll
    for (int rt = 0; rt < 4; rt++)
#pragma unroll
        for (int c = 0; c < 2; c++)
#pragma unroll
            for (int r = 0; r < 4; r++) {
                int row = rt * 16 + q * 4 + r, col = wc0 + c * 16 + l15;
                X0[row * LDX + col] = (bf16_t)silu_f(acc[rt][c][r]);
            }
    __syncthreads();

    // s2: res += silu(X0 @ Wb2 + bb2) ; X1 = bf16(res)
    mfma_stage<4>(X0, Wb2sw, lane, ct0, acc, bb2[wc0 + l15], bb2[wc0 + 16 + l15]);
#pragma unroll
    for (int rt = 0; rt < 4; rt++)
#pragma unroll
        for (int c = 0; c < 2; c++)
#pragma unroll
            for (int r = 0; r < 4; r++) {
                int row = rt * 16 + q * 4 + r, col = wc0 + c * 16 + l15;
                float v = res[rt][c][r] + silu_f(acc[rt][c][r]);
                res[rt][c][r] = v;
                X1[row * LDX + col] = (bf16_t)v;
            }
    __syncthreads();

    // s3: res = silu(X1 @ W_final + b_final) + m ; X0 = bf16(res)
    mfma_stage<4>(X1, Wfinsw, lane, ct0, acc, b_final[wc0 + l15], b_final[wc0 + 16 + l15]);
#pragma unroll
    for (int rt = 0; rt < 4; rt++)
#pragma unroll
        for (int c = 0; c < 2; c++)
#pragma unroll
            for (int r = 0; r < 4; r++) {
                int row = rt * 16 + q * 4 + r, col = wc0 + c * 16 + l15;
                float v = silu_f(acc[rt][c][r]) + m[(size_t)(r0 + row) * 128 + col];
                res[rt][c][r] = v;
                X0[row * LDX + col] = (bf16_t)v;
            }
    __syncthreads();

    // s4: H = silu(X0 @ Wa1[0] + ba1[0]) -> X1
    mfma_stage<4>(X0, Wa1s0, lane, ct0, acc, ba1[wc0 + l15], ba1[wc0 + 16 + l15]);
#pragma unroll
    for (int rt = 0; rt < 4; rt++)
#pragma unroll
        for (int c = 0; c < 2; c++)
#pragma unroll
            for (int r = 0; r < 4; r++) {
                int row = rt * 16 + q * 4 + r, col = wc0 + c * 16 + l15;
                X1[row * LDX + col] = (bf16_t)silu_f(acc[rt][c][r]);
            }
    __syncthreads();

    // s5: res += silu(X1 @ Wa2[0] + ba2[0]) ; X0 = bf16(res)
    mfma_stage<4>(X1, Wa2s0, lane, ct0, acc, ba2[wc0 + l15], ba2[wc0 + 16 + l15]);
#pragma unroll
    for (int rt = 0; rt < 4; rt++)
#pragma unroll
        for (int c = 0; c < 2; c++)
#pragma unroll
            for (int r = 0; r < 4; r++) {
                int row = rt * 16 + q * 4 + r, col = wc0 + c * 16 + l15;
                float v = res[rt][c][r] + silu_f(acc[rt][c][r]);
                res[rt][c][r] = v;
                X0[row * LDX + col] = (bf16_t)v;
            }
    __syncthreads();

    // s6: H = silu(X0 @ Wa1[1] + ba1[1]) -> X1
    mfma_stage<4>(X0, Wa1s1, lane, ct0, acc, ba1[128 + wc0 + l15], ba1[128 + wc0 + 16 + l15]);
#pragma unroll
    for (int rt = 0; rt < 4; rt++)
#pragma unroll
        for (int c = 0; c < 2; c++)
#pragma unroll
            for (int r = 0; r < 4; r++) {
                int row = rt * 16 + q * 4 + r, col = wc0 + c * 16 + l15;
                X1[row * LDX + col] = (bf16_t)silu_f(acc[rt][c][r]);
            }
    __syncthreads();

    // s7: out = res + silu(X1 @ Wa2[1] + ba2[1])
    mfma_stage<4>(X1, Wa2s1, lane, ct0, acc, ba2[128 + wc0 + l15], ba2[128 + wc0 + 16 + l15]);
#pragma unroll
    for (int rt = 0; rt < 4; rt++)
#pragma unroll
        for (int c = 0; c < 2; c++)
#pragma unroll
            for (int r = 0; r < 4; r++) {
                int row = rt * 16 + q * 4 + r, col = wc0 + c * 16 + l15;
                out[(size_t)(r0 + row) * 128 + col] = res[rt][c][r] + silu_f(acc[rt][c][r]);
            }
}

extern "C" void kernel_launch(void* const* d_in, const int* in_sizes, int n_in,
                              void* d_out, int out_size, void* d_ws, size_t ws_size,
                              hipStream_t stream) {
    const float* m      = (const float*)d_in[0];
    const float* rbf    = (const float*)d_in[1];
    const float* sbf    = (const float*)d_in[2];
    const int*   src    = (const int*)d_in[3];
    const int*   dst    = (const int*)d_in[4];
    const float* W_rbf1 = (const float*)d_in[5];
    const float* W_rbf2 = (const float*)d_in[6];
    const float* W_sbf1 = (const float*)d_in[7];
    const float* W_sbf2 = (const float*)d_in[8];
    const float* W_ji   = (const float*)d_in[9];
    const float* b_ji   = (const float*)d_in[10];
    const float* W_kj   = (const float*)d_in[11];
    const float* b_kj   = (const float*)d_in[12];
    const float* W_down = (const float*)d_in[13];
    const float* W_up   = (const float*)d_in[14];
    const float* Wb1    = (const float*)d_in[15];
    const float* bb1    = (const float*)d_in[16];
    const float* Wb2    = (const float*)d_in[17];
    const float* bb2    = (const float*)d_in[18];
    const float* W_final= (const float*)d_in[19];
    const float* b_final= (const float*)d_in[20];
    const float* Wa1    = (const float*)d_in[21];
    const float* ba1    = (const float*)d_in[22];
    const float* Wa2    = (const float*)d_in[23];
    const float* ba2    = (const float*)d_in[24];
    float* out = (float*)d_out;

    // ws layout:
    //   x_ji bf16 [E,128] | x_kj f16 [E,64] | m_upd bf16 [E,64]
    //   | Bs bf16 [T,8] (CSR order) | srcrec int [T]
    //   | counts int [E] | offs int [E] | cursor int [E]
    //   | bsums int[256]+bsums2 int[256] | swizzled weights
    size_t off_xkj  = (size_t)E_N * 128 * sizeof(bf16_t);
    size_t off_mup  = off_xkj  + (size_t)E_N * 64 * sizeof(f16_t);
    size_t off_Bs   = off_mup  + (size_t)E_N * 64 * sizeof(bf16_t);
    size_t off_src  = off_Bs   + (size_t)T_N * 8 * sizeof(bf16_t);
    size_t off_cnt  = off_src  + (size_t)T_N * sizeof(int);
    size_t off_offs = off_cnt  + (size_t)E_N * sizeof(int);
    size_t off_cur  = off_offs + (size_t)E_N * sizeof(int);
    size_t off_bs   = off_cur  + (size_t)E_N * sizeof(int);
    size_t off_w    = off_bs   + 4096;
    size_t w_elems = 167936;
    if (ws_size < off_w + w_elems * sizeof(bf16_t)) return;

    bf16_t* x_ji_bf = (bf16_t*)d_ws;
    f16_t*  x_kj    = (f16_t*)((char*)d_ws + off_xkj);
    bf16_t* m_upd   = (bf16_t*)((char*)d_ws + off_mup);
    bf16_t* Bs      = (bf16_t*)((char*)d_ws + off_Bs);
    int*    srcrec  = (int*)((char*)d_ws + off_src);
    int*    counts  = (int*)((char*)d_ws + off_cnt);
    int*    offs    = (int*)((char*)d_ws + off_offs);
    int*    cursor  = (int*)((char*)d_ws + off_cur);
    int*    bsums   = (int*)((char*)d_ws + off_bs);
    int*    bsums2  = bsums + 256;
    bf16_t* wts     = (bf16_t*)((char*)d_ws + off_w);

    bf16_t* W_rbf2sw = wts;            // 8 frags   (K 8->32 pad, N=128)
    bf16_t* W_jisw   = wts + 4096;     // 32 frags
    bf16_t* W_kjsw   = wts + 20480;    // 32
    bf16_t* W_downsw = wts + 36864;    // 16 (K=128, N=64)
    bf16_t* W_upsw   = wts + 45056;    // 16 (K=64, N=128)
    bf16_t* Wb1sw    = wts + 53248;
    bf16_t* Wb2sw    = wts + 69632;
    bf16_t* Wfinsw   = wts + 86016;
    bf16_t* Wa1sw0   = wts + 102400;
    bf16_t* Wa1sw1   = wts + 118784;
    bf16_t* Wa2sw0   = wts + 135168;
    bf16_t* Wa2sw1   = wts + 151552;

    SwArgs sa;
    int tb = 0;
    auto set = [&](int i, const float* s, bf16_t* d, int Ksrc, int KK, int N) {
        sa.d[i] = SwDesc{s, d, Ksrc, KK, N, tb};
        tb += (N / 16) * KK * 64;
    };
    set(0,  W_rbf2,        W_rbf2sw, 8,   1, 128);
    set(1,  W_ji,          W_jisw,   128, 4, 128);
    set(2,  W_kj,          W_kjsw,   128, 4, 128);
    set(3,  W_down,        W_downsw, 128, 4, 64);
    set(4,  W_up,          W_upsw,   64,  2, 128);
    set(5,  Wb1,           Wb1sw,    128, 4, 128);
    set(6,  Wb2,           Wb2sw,    128, 4, 128);
    set(7,  W_final,       Wfinsw,   128, 4, 128);
    set(8,  Wa1,           Wa1sw0,   128, 4, 128);
    set(9,  Wa1 + 16384,   Wa1sw1,   128, 4, 128);
    set(10, Wa2,           Wa2sw0,   128, 4, 128);
    set(11, Wa2 + 16384,   Wa2sw1,   128, 4, 128);
    int total = tb;  // 20992

    swizzle_kernel<<<(total + 255) / 256, 256, 0, stream>>>(sa, total);

    // zero counts (E ints = 65536 float4)
    zero_kernel<<<256, 256, 0, stream>>>((float4*)counts, E_N / 4);

    // CSR build (fused B-factor scatter)
    hist_kernel<<<T_N / 256, 256, 0, stream>>>(dst, counts);
    scan1_kernel<<<E_N / 1024, 256, 0, stream>>>((const int4*)counts, offs, bsums);
    scan2_kernel<<<1, 256, 0, stream>>>(bsums, bsums2);
    scan3_kernel<<<E_N / 256, 256, 0, stream>>>(offs, bsums2, cursor);
    fillB_kernel<<<T_N / 64, 256, 0, stream>>>(sbf, src, dst, W_sbf1,
                                               cursor, srcrec, Bs);

    edge_kernel<<<E_N / 64, 256, 0, stream>>>(m, rbf, W_rbf1, W_rbf2sw,
                                              W_jisw, b_ji, W_kjsw, b_kj, W_downsw,
                                              x_ji_bf, x_kj);

    gather_kernel<<<E_N / 4, 256, 0, stream>>>(offs, counts, srcrec,
                                               Bs, W_sbf2, x_kj, m_upd);

    post_kernel<<<E_N / 64, 256, 0, stream>>>(m, x_ji_bf, m_upd, W_upsw,
                                              Wb1sw, bb1, Wb2sw, bb2,
                                              Wfinsw, b_final,
                                              Wa1sw0, Wa1sw1, ba1,
                                              Wa2sw0, Wa2sw1, ba2, out);
}